// Round 8
// baseline (214.833 us; speedup 1.0000x reference)
//
#include <hip/hip_runtime.h>
#include <hip/hip_fp16.h>

#define NLEVELS 8
#define NBY     64
#define NBX     16
#define NBINS   (NBY * NBX)
#define CHUNK   1024   // samples per block in scatter (4 iters x 256 threads)

// RESOLUTIONS = [16, 29, 53, 98, 181, 332, 610, 1120]
__constant__ int   c_res[NLEVELS]   = {16, 29, 53, 98, 181, 332, 610, 1120};
__constant__ float c_scale[NLEVELS] = {7.5f, 14.0f, 26.0f, 48.5f, 90.0f, 165.5f, 304.5f, 559.5f};
__constant__ int   c_cum[NLEVELS]   = {0, 256, 1097, 3906, 13510, 46271, 156495, 528595};
#define TOTAL_TEXELS 1782995

typedef float        f32x4 __attribute__((ext_vector_type(4)));
typedef float        f32x2 __attribute__((ext_vector_type(2)));
typedef unsigned int u32;
typedef u32          u32x4 __attribute__((ext_vector_type(4), aligned(8)));  // 8-B-aligned 16-B load

struct CbPtrs { const float* cb[NLEVELS]; };

__device__ __forceinline__ float2 up_h2(u32 v) {
    __half2 h = *reinterpret_cast<__half2*>(&v);
    return __half22float2(h);
}

// y-major 2D bin: keeps XCD-contiguous y-bands, adds x locality for L1 residency
__device__ __forceinline__ int bin_of(float cx, float cy) {
    int by = min(NBY - 1, max(0, (int)((cy + 1.0f) * (0.5f * NBY))));
    int bx = min(NBX - 1, max(0, (int)((cx + 1.0f) * (0.5f * NBX))));
    return by * NBX + bx;
}

// ---------------- transpose [4,R,R] fp32 -> [R,R,4] fp16 texels (8B uint2) ----------------
__global__ __launch_bounds__(256) void transpose_cbs(CbPtrs p, uint2* __restrict__ tcb, int total) {
    for (int t = blockIdx.x * blockDim.x + threadIdx.x; t < total; t += gridDim.x * blockDim.x) {
        int L = 0;
#pragma unroll
        for (int i = 1; i < NLEVELS; ++i) if (t >= c_cum[i]) L = i;
        int i  = t - c_cum[L];
        int rr = c_res[L] * c_res[L];
        const float* cb = p.cb[L];
        __half2 h01 = __floats2half2_rn(cb[i],          cb[i + rr]);
        __half2 h23 = __floats2half2_rn(cb[i + 2 * rr], cb[i + 3 * rr]);
        uint2 tex;
        tex.x = *reinterpret_cast<u32*>(&h01);
        tex.y = *reinterpret_cast<u32*>(&h23);
        tcb[t] = tex;
    }
}

// ---------------- binning ----------------
__global__ __launch_bounds__(256) void zero_counts(u32* gcount) {
    int i = blockIdx.x * 256 + threadIdx.x;
    if (i < NBINS) gcount[i] = 0u;
}

__global__ __launch_bounds__(256) void hist_kernel(const float2* __restrict__ coords,
                                                   u32* __restrict__ gcount, int S) {
    __shared__ u32 h[NBINS];
    for (int i = threadIdx.x; i < NBINS; i += 256) h[i] = 0u;
    __syncthreads();
    for (int s = blockIdx.x * 256 + threadIdx.x; s < S; s += gridDim.x * 256) {
        float2 c = coords[s];
        atomicAdd(&h[bin_of(c.x, c.y)], 1u);
    }
    __syncthreads();
    for (int i = threadIdx.x; i < NBINS; i += 256)
        if (h[i]) atomicAdd(&gcount[i], h[i]);
}

// 1 block x 256 threads: exclusive scan of NBINS=1024 counters (4 per thread)
__global__ __launch_bounds__(256) void scan_kernel(const u32* __restrict__ gcount,
                                                   u32* __restrict__ gcursor) {
    __shared__ u32 sums[256];
    int i = threadIdx.x;
    u32 v0 = gcount[4 * i], v1 = gcount[4 * i + 1], v2 = gcount[4 * i + 2], v3 = gcount[4 * i + 3];
    u32 p1 = v0, p2 = v0 + v1, p3 = v0 + v1 + v2;
    sums[i] = p3 + v3;
    __syncthreads();
    for (int off = 1; off < 256; off <<= 1) {
        u32 x = (i >= off) ? sums[i - off] : 0u;
        __syncthreads();
        sums[i] += x;
        __syncthreads();
    }
    u32 base = (i == 0) ? 0u : sums[i - 1];
    gcursor[4 * i]     = base;
    gcursor[4 * i + 1] = base + p1;
    gcursor[4 * i + 2] = base + p2;
    gcursor[4 * i + 3] = base + p3;
}

__global__ __launch_bounds__(256) void scatter_kernel(const float2* __restrict__ coords,
                                                      u32* __restrict__ gcursor,
                                                      float2* __restrict__ coordsS,
                                                      int*    __restrict__ idxS, int S) {
    __shared__ u32 h[NBINS];
    __shared__ u32 rank_base[NBINS];
    int s0 = blockIdx.x * CHUNK;
    for (int i = threadIdx.x; i < NBINS; i += 256) h[i] = 0u;
    __syncthreads();
    u32 myrank[CHUNK / 256];
    int myk[CHUNK / 256];
    float2 myc[CHUNK / 256];
#pragma unroll
    for (int it = 0; it < CHUNK / 256; ++it) {
        int s = s0 + it * 256 + threadIdx.x;
        if (s < S) {
            float2 c = coords[s];
            int k = bin_of(c.x, c.y);
            myc[it] = c;
            myk[it] = k;
            myrank[it] = atomicAdd(&h[k], 1u);
        }
    }
    __syncthreads();
    for (int i = threadIdx.x; i < NBINS; i += 256)
        rank_base[i] = h[i] ? atomicAdd(&gcursor[i], h[i]) : 0u;
    __syncthreads();
#pragma unroll
    for (int it = 0; it < CHUNK / 256; ++it) {
        int s = s0 + it * 256 + threadIdx.x;
        if (s < S) {
            u32 pos = rank_base[myk[it]] + myrank[it];
            coordsS[pos] = myc[it];
            idxS[pos]    = s;
        }
    }
}

// ------- main: 2D-bin-sorted samples, 8 threads per sample (one per level) -------
// Lanes 8k..8k+7 share sample s: one store instruction fully covers 8 samples
// x 128 B contiguous -> full-line coalesced writes. Per-bin fine-level windows
// (~16 KB) are L1-resident -> gathers mostly L1 hits.
__global__ __launch_bounds__(256) void grid_sorted8(const f32x2* __restrict__ coordsS,
                                                    const int*   __restrict__ idxS,
                                                    const uint2* __restrict__ tcb,
                                                    f32x4* __restrict__ out, int S) {
    // XCD-contiguous swizzle: physical block p runs on XCD p%8; give each XCD a
    // contiguous logical range so its concurrent working set is ~1/8 of the sort.
    int p  = blockIdx.x;
    int nb = gridDim.x;                  // multiple of 8
    int b  = (p & 7) * (nb >> 3) + (p >> 3);
    int t  = b * 256 + threadIdx.x;
    int s  = t >> 3;
    if (s >= S) return;
    int L  = t & 7;

    f32x2 c = coordsS[s];                // 8 lanes same 8-B addr (L1 broadcast)
    int idx = idxS[s];

    int   res   = c_res[L];
    float scale = c_scale[L];
    const uint2* __restrict__ base = tcb + c_cum[L];

    float px = (c.x + 1.0f) * scale;
    float py = (c.y + 1.0f) * scale;
    float xf = floorf(px), yf = floorf(py);
    float wx = px - xf,    wy = py - yf;
    int x0 = (int)xf, y0 = (int)yf;
    int xp = min(max(x0, 0), res - 2);  wx += (float)(x0 - xp);
    int yp = min(max(y0, 0), res - 2);  wy += (float)(y0 - yp);
    const uint2* r0 = base + yp * res + xp;
    u32x4 t0 = *(const u32x4*)r0;          // texels (xp,yp),(xp+1,yp)
    u32x4 t1 = *(const u32x4*)(r0 + res);  // texels (xp,yp+1),(xp+1,yp+1)

    float2 a00 = up_h2(t0.x), b00 = up_h2(t0.y);
    float2 a01 = up_h2(t0.z), b01 = up_h2(t0.w);
    float2 a10 = up_h2(t1.x), b10 = up_h2(t1.y);
    float2 a11 = up_h2(t1.z), b11 = up_h2(t1.w);

    float w00 = (1.0f - wx) * (1.0f - wy);
    float w01 = wx * (1.0f - wy);
    float w10 = (1.0f - wx) * wy;
    float w11 = wx * wy;

    f32x4 r;
    r.x = a00.x * w00 + a01.x * w01 + a10.x * w10 + a11.x * w11;
    r.y = a00.y * w00 + a01.y * w01 + a10.y * w10 + a11.y * w11;
    r.z = b00.x * w00 + b01.x * w01 + b10.x * w10 + b11.x * w11;
    r.w = b00.y * w00 + b01.y * w01 + b10.y * w10 + b11.y * w11;

    out[(size_t)idx * 8 + L] = r;
}

// ---------------- unsorted fallback (ws too small for bins) ----------------
__global__ __launch_bounds__(256) void grid_main(const float2* __restrict__ coords,
                                                 const uint2* __restrict__ tcb,
                                                 f32x4* __restrict__ out4, int S) {
    int t = blockIdx.x * 256 + threadIdx.x;
    if (t >= S * 8) return;
    int L = t & 7;
    int s = t >> 3;
    float2 c = coords[s];
    int   res   = c_res[L];
    float scale = c_scale[L];
    const uint2* __restrict__ base = tcb + c_cum[L];
    float px = (c.x + 1.0f) * scale;
    float py = (c.y + 1.0f) * scale;
    float xf = floorf(px), yf = floorf(py);
    float wx = px - xf,    wy = py - yf;
    int x0 = (int)xf, y0 = (int)yf;
    int xp = min(max(x0, 0), res - 2);  wx += (float)(x0 - xp);
    int yp = min(max(y0, 0), res - 2);  wy += (float)(y0 - yp);
    const uint2* r0 = base + yp * res + xp;
    u32x4 t0 = *(const u32x4*)r0;
    u32x4 t1 = *(const u32x4*)(r0 + res);
    float2 a00 = up_h2(t0.x), b00 = up_h2(t0.y);
    float2 a01 = up_h2(t0.z), b01 = up_h2(t0.w);
    float2 a10 = up_h2(t1.x), b10 = up_h2(t1.y);
    float2 a11 = up_h2(t1.z), b11 = up_h2(t1.w);
    float w00 = (1.0f - wx) * (1.0f - wy);
    float w01 = wx * (1.0f - wy);
    float w10 = (1.0f - wx) * wy;
    float w11 = wx * wy;
    f32x4 r;
    r.x = a00.x * w00 + a01.x * w01 + a10.x * w10 + a11.x * w11;
    r.y = a00.y * w00 + a01.y * w01 + a10.y * w10 + a11.y * w11;
    r.z = b00.x * w00 + b01.x * w01 + b10.x * w10 + b11.x * w11;
    r.w = b00.y * w00 + b01.y * w01 + b10.y * w10 + b11.y * w11;
    out4[t] = r;
}

// ---------------- generic levels fallback (levels != 8, raw fp32 cbs) ----------------
__global__ __launch_bounds__(256) void grid_generic(const float2* __restrict__ coords,
                                                    CbPtrs p, float4* __restrict__ out4,
                                                    int S, int levels) {
    int s = blockIdx.x * 256 + threadIdx.x;
    if (s >= S) return;
    float2 c = coords[s];
    for (int L = 0; L < levels; ++L) {
        int   res   = c_res[L];
        float scale = c_scale[L];
        float px = (c.x + 1.0f) * scale;
        float py = (c.y + 1.0f) * scale;
        float x0f = floorf(px), y0f = floorf(py);
        float wx = px - x0f,    wy = py - y0f;
        int rm1 = res - 1;
        int x0 = min(max((int)x0f, 0), rm1);
        int x1 = min(x0 + 1, rm1);
        int y0 = min(max((int)y0f, 0), rm1);
        int y1 = min(y0 + 1, rm1);
        int i00 = y0 * res + x0, i01 = y0 * res + x1, i10 = y1 * res + x0, i11 = y1 * res + x1;
        float w00 = (1.0f - wx) * (1.0f - wy);
        float w01 = wx * (1.0f - wy);
        float w10 = (1.0f - wx) * wy;
        float w11 = wx * wy;
        float4 r;
        const float* cb = p.cb[L];
        int rr = res * res;
        float* pr = &r.x;
#pragma unroll
        for (int f = 0; f < 4; ++f) {
            const float* cf = cb + f * rr;
            pr[f] = cf[i00] * w00 + cf[i01] * w01 + cf[i10] * w10 + cf[i11] * w11;
        }
        out4[(size_t)s * levels + L] = r;
    }
}

extern "C" void kernel_launch(void* const* d_in, const int* in_sizes, int n_in,
                              void* d_out, int out_size, void* d_ws, size_t ws_size,
                              hipStream_t stream) {
    const float2* coords = (const float2*)d_in[0];
    int S = in_sizes[0] / 2;                 // total samples B*N
    int levels = out_size / (S * 4);

    CbPtrs ptrs;
    for (int i = 0; i < NLEVELS; ++i) ptrs.cb[i] = (const float*)d_in[2 + i];

    // ws layout
    size_t tcb_bytes  = ((size_t)TOTAL_TEXELS * 8 + 255) & ~(size_t)255;
    size_t cnt_bytes  = (size_t)NBINS * 2 * 4;      // gcount + gcursor
    size_t crd_bytes  = (size_t)S * 8;
    size_t idx_bytes  = (size_t)S * 4;
    size_t need_sorted = tcb_bytes + cnt_bytes + crd_bytes + idx_bytes;

    char* ws = (char*)d_ws;
    uint2*  tcb     = (uint2*)ws;
    u32*    gcount  = (u32*)(ws + tcb_bytes);
    u32*    gcursor = gcount + NBINS;
    float2* coordsS = (float2*)(ws + tcb_bytes + cnt_bytes);
    int*    idxS    = (int*)(ws + tcb_bytes + cnt_bytes + crd_bytes);

    if (levels != NLEVELS) {
        int blocks = (S + 255) / 256;
        grid_generic<<<blocks, 256, 0, stream>>>(coords, ptrs, (float4*)d_out, S, levels);
        return;
    }
    if (ws_size < tcb_bytes) {
        int blocks = (S + 255) / 256;
        grid_generic<<<blocks, 256, 0, stream>>>(coords, ptrs, (float4*)d_out, S, levels);
        return;
    }

    int tg = (TOTAL_TEXELS + 255) / 256;
    transpose_cbs<<<tg, 256, 0, stream>>>(ptrs, tcb, TOTAL_TEXELS);

    if (ws_size >= need_sorted) {
        int nchunk = (S + CHUNK - 1) / CHUNK;
        zero_counts<<<(NBINS + 255) / 256, 256, 0, stream>>>(gcount);
        hist_kernel<<<512, 256, 0, stream>>>(coords, gcount, S);
        scan_kernel<<<1, 256, 0, stream>>>(gcount, gcursor);
        scatter_kernel<<<nchunk, 256, 0, stream>>>(coords, gcursor, coordsS, idxS, S);
        long long total = (long long)S * 8;
        int nb = (int)((total + 255) / 256);
        nb = ((nb + 7) / 8) * 8;             // multiple of 8 for bijective swizzle
        grid_sorted8<<<nb, 256, 0, stream>>>((const f32x2*)coordsS, idxS, tcb, (f32x4*)d_out, S);
    } else {
        long long total = (long long)S * 8;
        int blocks = (int)((total + 255) / 256);
        grid_main<<<blocks, 256, 0, stream>>>(coords, tcb, (f32x4*)d_out, S);
    }
}

// Round 9
// 203.495 us; speedup vs baseline: 1.0557x; 1.0557x over previous
//
#include <hip/hip_runtime.h>
#include <hip/hip_fp16.h>

#define NLEVELS 8
#define NBY     64
#define NBX     64
#define NBINS   (NBY * NBX)
#define CHUNK   1024   // samples per block in scatter (4 iters x 256 threads)
#define WINMAX  1024   // LDS window texels (worst case 940)

// RESOLUTIONS = [16, 29, 53, 98, 181, 332, 610, 1120]
__constant__ int   c_res[NLEVELS]   = {16, 29, 53, 98, 181, 332, 610, 1120};
__constant__ float c_scale[NLEVELS] = {7.5f, 14.0f, 26.0f, 48.5f, 90.0f, 165.5f, 304.5f, 559.5f};
__constant__ int   c_cum[NLEVELS]   = {0, 256, 1097, 3906, 13510, 46271, 156495, 528595};
#define TOTAL_TEXELS 1782995

typedef float        f32x4 __attribute__((ext_vector_type(4)));
typedef float        f32x2 __attribute__((ext_vector_type(2)));
typedef unsigned int u32;
typedef u32          u32x4 __attribute__((ext_vector_type(4)));
typedef u32          u32x4a8 __attribute__((ext_vector_type(4), aligned(8)));

struct CbPtrs { const float* cb[NLEVELS]; };

__device__ __forceinline__ float2 up_h2(u32 v) {
    __half2 h = *reinterpret_cast<__half2*>(&v);
    return __half22float2(h);
}

// y-major 2D bin (64x64)
__device__ __forceinline__ int bin_of(float cx, float cy) {
    int by = min(NBY - 1, max(0, (int)((cy + 1.0f) * (0.5f * NBY))));
    int bx = min(NBX - 1, max(0, (int)((cx + 1.0f) * (0.5f * NBX))));
    return by * NBX + bx;
}

// ---------------- transpose [4,R,R] fp32 -> [R,R,4] fp16 texels (8B uint2) ----------------
__global__ __launch_bounds__(256) void transpose_cbs(CbPtrs p, uint2* __restrict__ tcb, int total) {
    for (int t = blockIdx.x * blockDim.x + threadIdx.x; t < total; t += gridDim.x * blockDim.x) {
        int L = 0;
#pragma unroll
        for (int i = 1; i < NLEVELS; ++i) if (t >= c_cum[i]) L = i;
        int i  = t - c_cum[L];
        int rr = c_res[L] * c_res[L];
        const float* cb = p.cb[L];
        __half2 h01 = __floats2half2_rn(cb[i],          cb[i + rr]);
        __half2 h23 = __floats2half2_rn(cb[i + 2 * rr], cb[i + 3 * rr]);
        uint2 tex;
        tex.x = *reinterpret_cast<u32*>(&h01);
        tex.y = *reinterpret_cast<u32*>(&h23);
        tcb[t] = tex;
    }
}

// ---------------- binning ----------------
__global__ __launch_bounds__(256) void zero_counts(u32* gcount) {
    int i = blockIdx.x * 256 + threadIdx.x;
    if (i < NBINS) gcount[i] = 0u;
}

__global__ __launch_bounds__(256) void hist_kernel(const float2* __restrict__ coords,
                                                   u32* __restrict__ gcount, int S) {
    __shared__ u32 h[NBINS];
    for (int i = threadIdx.x; i < NBINS; i += 256) h[i] = 0u;
    __syncthreads();
    for (int s = blockIdx.x * 256 + threadIdx.x; s < S; s += gridDim.x * 256) {
        float2 c = coords[s];
        atomicAdd(&h[bin_of(c.x, c.y)], 1u);
    }
    __syncthreads();
    for (int i = threadIdx.x; i < NBINS; i += 256)
        if (h[i]) atomicAdd(&gcount[i], h[i]);
}

// 1 block x 256 threads: exclusive scan of NBINS=4096 (16 per thread)
__global__ __launch_bounds__(256) void scan_kernel(const u32* __restrict__ gcount,
                                                   u32* __restrict__ gcursor) {
    __shared__ u32 sums[256];
    int i = threadIdx.x;
    u32 loc[16];
    u32 acc = 0;
#pragma unroll
    for (int k = 0; k < 16; ++k) { loc[k] = acc; acc += gcount[i * 16 + k]; }
    sums[i] = acc;
    __syncthreads();
    for (int off = 1; off < 256; off <<= 1) {
        u32 x = (i >= off) ? sums[i - off] : 0u;
        __syncthreads();
        sums[i] += x;
        __syncthreads();
    }
    u32 base = (i == 0) ? 0u : sums[i - 1];
#pragma unroll
    for (int k = 0; k < 16; ++k) gcursor[i * 16 + k] = base + loc[k];
}

// scatter: packed 16-B records {bits(cx), bits(cy), idx, 0}
__global__ __launch_bounds__(256) void scatter_kernel(const float2* __restrict__ coords,
                                                      u32* __restrict__ gcursor,
                                                      u32x4* __restrict__ recS, int S) {
    __shared__ u32 h[NBINS];
    __shared__ u32 rank_base[NBINS];
    int s0 = blockIdx.x * CHUNK;
    for (int i = threadIdx.x; i < NBINS; i += 256) h[i] = 0u;
    __syncthreads();
    u32 myrank[CHUNK / 256];
    int myk[CHUNK / 256];
    float2 myc[CHUNK / 256];
#pragma unroll
    for (int it = 0; it < CHUNK / 256; ++it) {
        int s = s0 + it * 256 + threadIdx.x;
        if (s < S) {
            float2 c = coords[s];
            int k = bin_of(c.x, c.y);
            myc[it] = c;
            myk[it] = k;
            myrank[it] = atomicAdd(&h[k], 1u);
        }
    }
    __syncthreads();
    for (int i = threadIdx.x; i < NBINS; i += 256)
        rank_base[i] = h[i] ? atomicAdd(&gcursor[i], h[i]) : 0u;
    __syncthreads();
#pragma unroll
    for (int it = 0; it < CHUNK / 256; ++it) {
        int s = s0 + it * 256 + threadIdx.x;
        if (s < S) {
            u32 pos = rank_base[myk[it]] + myrank[it];
            u32x4 r;
            r.x = __float_as_uint(myc[it].x);
            r.y = __float_as_uint(myc[it].y);
            r.z = (u32)s;
            r.w = 0u;
            recS[pos] = r;
        }
    }
}

// ------- main: block-per-bin, LDS-staged windows for all 8 levels -------
// 8 threads per sample (one per level). All bilinear gathers hit LDS;
// global traffic = coalesced window staging + record stream + full-line stores.
__global__ __launch_bounds__(256) void grid_bins(const u32x4* __restrict__ recS,
                                                 const uint2* __restrict__ tcb,
                                                 const u32*   __restrict__ gcount,
                                                 const u32*   __restrict__ gcursor,
                                                 f32x4* __restrict__ out) {
    __shared__ uint2 win[WINMAX];
    __shared__ int s_xlo[8], s_ylo[8], s_w[8], s_h[8], s_off[8];

    // XCD-contiguous swizzle over bins (gridDim.x == NBINS, multiple of 8)
    int p  = blockIdx.x;
    int nb = gridDim.x;
    int b  = (p & 7) * (nb >> 3) + (p >> 3);
    int by = b >> 6, bx = b & 63;

    if (threadIdx.x == 0) {
        int tot = 0;
#pragma unroll
        for (int L = 0; L < NLEVELS; ++L) {
            int   res = c_res[L];
            float sc  = c_scale[L] * (1.0f / 32.0f);   // scale per bin step
            int xl = (int)floorf(bx * sc) - 1;        if (xl < 0) xl = 0;
            int xh = (int)floorf((bx + 1) * sc) + 2;  if (xh > res - 1) xh = res - 1;
            int yl = (int)floorf(by * sc) - 1;        if (yl < 0) yl = 0;
            int yh = (int)floorf((by + 1) * sc) + 2;  if (yh > res - 1) yh = res - 1;
            s_xlo[L] = xl; s_ylo[L] = yl;
            s_w[L] = xh - xl + 1; s_h[L] = yh - yl + 1;
            s_off[L] = tot; tot += s_w[L] * s_h[L];
        }
    }
    __syncthreads();

    // stage windows (coalesced row strips)
#pragma unroll 1
    for (int L = 0; L < NLEVELS; ++L) {
        int w = s_w[L], n = w * s_h[L];
        int res = c_res[L];
        const uint2* src = tcb + c_cum[L] + s_ylo[L] * res + s_xlo[L];
        int o = s_off[L];
        for (int i = threadIdx.x; i < n; i += 256) {
            int yy = i / w, xx = i - yy * w;
            win[o + i] = src[yy * res + xx];
        }
    }
    __syncthreads();

    u32 end = gcursor[b], cnt = gcount[b];
    u32 start = end - cnt;
    u32 ntask = cnt * 8u;
    for (u32 t = threadIdx.x; t < ntask; t += 256u) {
        u32 s = start + (t >> 3);
        int L = (int)(t & 7u);
        u32x4 rec = *(const u32x4*)&recS[s];   // 8 lanes same record (broadcast)
        float cx = __uint_as_float(rec.x);
        float cy = __uint_as_float(rec.y);
        int  idx = (int)rec.z;

        int   res   = c_res[L];
        float scale = c_scale[L];
        float px = (cx + 1.0f) * scale;
        float py = (cy + 1.0f) * scale;
        float xf = floorf(px), yf = floorf(py);
        float wx = px - xf,    wy = py - yf;
        int x0 = (int)xf, y0 = (int)yf;
        int xp = min(max(x0, 0), res - 2);  wx += (float)(x0 - xp);
        int yp = min(max(y0, 0), res - 2);  wy += (float)(y0 - yp);

        int w    = s_w[L];
        int base = s_off[L] + (yp - s_ylo[L]) * w + (xp - s_xlo[L]);
        uint2 t00 = win[base],     t01 = win[base + 1];
        uint2 t10 = win[base + w], t11 = win[base + w + 1];

        float2 a00 = up_h2(t00.x), b00 = up_h2(t00.y);
        float2 a01 = up_h2(t01.x), b01 = up_h2(t01.y);
        float2 a10 = up_h2(t10.x), b10 = up_h2(t10.y);
        float2 a11 = up_h2(t11.x), b11 = up_h2(t11.y);

        float w00 = (1.0f - wx) * (1.0f - wy);
        float w01 = wx * (1.0f - wy);
        float w10 = (1.0f - wx) * wy;
        float w11 = wx * wy;

        f32x4 r;
        r.x = a00.x * w00 + a01.x * w01 + a10.x * w10 + a11.x * w11;
        r.y = a00.y * w00 + a01.y * w01 + a10.y * w10 + a11.y * w11;
        r.z = b00.x * w00 + b01.x * w01 + b10.x * w10 + b11.x * w11;
        r.w = b00.y * w00 + b01.y * w01 + b10.y * w10 + b11.y * w11;

        out[(size_t)idx * 8 + L] = r;
    }
}

// ---------------- unsorted fallback (ws too small for bins) ----------------
__global__ __launch_bounds__(256) void grid_main(const float2* __restrict__ coords,
                                                 const uint2* __restrict__ tcb,
                                                 f32x4* __restrict__ out4, int S) {
    int t = blockIdx.x * 256 + threadIdx.x;
    if (t >= S * 8) return;
    int L = t & 7;
    int s = t >> 3;
    float2 c = coords[s];
    int   res   = c_res[L];
    float scale = c_scale[L];
    const uint2* __restrict__ base = tcb + c_cum[L];
    float px = (c.x + 1.0f) * scale;
    float py = (c.y + 1.0f) * scale;
    float xf = floorf(px), yf = floorf(py);
    float wx = px - xf,    wy = py - yf;
    int x0 = (int)xf, y0 = (int)yf;
    int xp = min(max(x0, 0), res - 2);  wx += (float)(x0 - xp);
    int yp = min(max(y0, 0), res - 2);  wy += (float)(y0 - yp);
    const uint2* r0 = base + yp * res + xp;
    u32x4a8 t0 = *(const u32x4a8*)r0;
    u32x4a8 t1 = *(const u32x4a8*)(r0 + res);
    float2 a00 = up_h2(t0.x), b00 = up_h2(t0.y);
    float2 a01 = up_h2(t0.z), b01 = up_h2(t0.w);
    float2 a10 = up_h2(t1.x), b10 = up_h2(t1.y);
    float2 a11 = up_h2(t1.z), b11 = up_h2(t1.w);
    float w00 = (1.0f - wx) * (1.0f - wy);
    float w01 = wx * (1.0f - wy);
    float w10 = (1.0f - wx) * wy;
    float w11 = wx * wy;
    f32x4 r;
    r.x = a00.x * w00 + a01.x * w01 + a10.x * w10 + a11.x * w11;
    r.y = a00.y * w00 + a01.y * w01 + a10.y * w10 + a11.y * w11;
    r.z = b00.x * w00 + b01.x * w01 + b10.x * w10 + b11.x * w11;
    r.w = b00.y * w00 + b01.y * w01 + b10.y * w10 + b11.y * w11;
    out4[t] = r;
}

// ---------------- generic levels fallback (levels != 8, raw fp32 cbs) ----------------
__global__ __launch_bounds__(256) void grid_generic(const float2* __restrict__ coords,
                                                    CbPtrs p, float4* __restrict__ out4,
                                                    int S, int levels) {
    int s = blockIdx.x * 256 + threadIdx.x;
    if (s >= S) return;
    float2 c = coords[s];
    for (int L = 0; L < levels; ++L) {
        int   res   = c_res[L];
        float scale = c_scale[L];
        float px = (c.x + 1.0f) * scale;
        float py = (c.y + 1.0f) * scale;
        float x0f = floorf(px), y0f = floorf(py);
        float wx = px - x0f,    wy = py - y0f;
        int rm1 = res - 1;
        int x0 = min(max((int)x0f, 0), rm1);
        int x1 = min(x0 + 1, rm1);
        int y0 = min(max((int)y0f, 0), rm1);
        int y1 = min(y0 + 1, rm1);
        int i00 = y0 * res + x0, i01 = y0 * res + x1, i10 = y1 * res + x0, i11 = y1 * res + x1;
        float w00 = (1.0f - wx) * (1.0f - wy);
        float w01 = wx * (1.0f - wy);
        float w10 = (1.0f - wx) * wy;
        float w11 = wx * wy;
        float4 r;
        const float* cb = p.cb[L];
        int rr = res * res;
        float* pr = &r.x;
#pragma unroll
        for (int f = 0; f < 4; ++f) {
            const float* cf = cb + f * rr;
            pr[f] = cf[i00] * w00 + cf[i01] * w01 + cf[i10] * w10 + cf[i11] * w11;
        }
        out4[(size_t)s * levels + L] = r;
    }
}

extern "C" void kernel_launch(void* const* d_in, const int* in_sizes, int n_in,
                              void* d_out, int out_size, void* d_ws, size_t ws_size,
                              hipStream_t stream) {
    const float2* coords = (const float2*)d_in[0];
    int S = in_sizes[0] / 2;                 // total samples B*N
    int levels = out_size / (S * 4);

    CbPtrs ptrs;
    for (int i = 0; i < NLEVELS; ++i) ptrs.cb[i] = (const float*)d_in[2 + i];

    // ws layout: tcb | gcount[NBINS] | gcursor[NBINS] | recS[S] (16 B each)
    size_t tcb_bytes  = ((size_t)TOTAL_TEXELS * 8 + 255) & ~(size_t)255;
    size_t cnt_bytes  = (size_t)NBINS * 2 * 4;
    size_t rec_bytes  = (size_t)S * 16;
    size_t need_sorted = tcb_bytes + cnt_bytes + rec_bytes;

    char* ws = (char*)d_ws;
    uint2* tcb     = (uint2*)ws;
    u32*   gcount  = (u32*)(ws + tcb_bytes);
    u32*   gcursor = gcount + NBINS;
    u32x4* recS    = (u32x4*)(ws + tcb_bytes + cnt_bytes);

    if (levels != NLEVELS || ws_size < tcb_bytes) {
        int blocks = (S + 255) / 256;
        grid_generic<<<blocks, 256, 0, stream>>>(coords, ptrs, (float4*)d_out, S, levels);
        return;
    }

    int tg = (TOTAL_TEXELS + 255) / 256;
    transpose_cbs<<<tg, 256, 0, stream>>>(ptrs, tcb, TOTAL_TEXELS);

    if (ws_size >= need_sorted) {
        int nchunk = (S + CHUNK - 1) / CHUNK;
        zero_counts<<<(NBINS + 255) / 256, 256, 0, stream>>>(gcount);
        hist_kernel<<<512, 256, 0, stream>>>(coords, gcount, S);
        scan_kernel<<<1, 256, 0, stream>>>(gcount, gcursor);
        scatter_kernel<<<nchunk, 256, 0, stream>>>(coords, gcursor, recS, S);
        grid_bins<<<NBINS, 256, 0, stream>>>(recS, tcb, gcount, gcursor, (f32x4*)d_out);
    } else {
        long long total = (long long)S * 8;
        int blocks = (int)((total + 255) / 256);
        grid_main<<<blocks, 256, 0, stream>>>(coords, tcb, (f32x4*)d_out, S);
    }
}

// Round 10
// 181.017 us; speedup vs baseline: 1.1868x; 1.1242x over previous
//
#include <hip/hip_runtime.h>
#include <hip/hip_fp16.h>

#define NLEVELS 8
#define NBANDS  64
#define CHUNK   1024   // samples per block in scatter (4 iters x 256 threads)

// RESOLUTIONS = [16, 29, 53, 98, 181, 332, 610, 1120]
__constant__ int   c_res[NLEVELS]   = {16, 29, 53, 98, 181, 332, 610, 1120};
__constant__ float c_scale[NLEVELS] = {7.5f, 14.0f, 26.0f, 48.5f, 90.0f, 165.5f, 304.5f, 559.5f};
// start offset of level L: quads for L0..6, texels for L7
__constant__ int   c_cum[NLEVELS]   = {0, 256, 1097, 3906, 13510, 46271, 156495, 528595};
#define QTOT    528595          // total quads, levels 0..6
#define L7RES   1120
#define L7TEX   (L7RES * L7RES) // 1254400 texels
#define QTAB_BYTES   ((size_t)QTOT * 32)
#define L7TAB_BYTES  ((size_t)L7TEX * 8)

typedef float        f32x4 __attribute__((ext_vector_type(4)));
typedef float        f32x2 __attribute__((ext_vector_type(2)));
typedef unsigned int u32;
typedef u32          u32x4a8 __attribute__((ext_vector_type(4), aligned(8)));

struct CbPtrs { const float* cb[NLEVELS]; };

__device__ __forceinline__ float2 up_h2(u32 v) {
    __half2 h = *reinterpret_cast<__half2*>(&v);
    return __half22float2(h);
}

__device__ __forceinline__ u32 pack_h2(float a, float b) {
    __half2 h = __floats2half2_rn(a, b);
    return *reinterpret_cast<u32*>(&h);
}

__device__ __forceinline__ int band_of(float cy) {
    float v = (cy + 1.0f) * 0.5f;
    int k = (int)(v * (float)NBANDS);
    return min(NBANDS - 1, max(0, k));
}

// ---------- fused prep: quad-table (L0-6) + L7 texel table + histogram ----------
#define PREP_TBLOCKS 1024
__global__ __launch_bounds__(256) void prep_kernel(CbPtrs p,
                                                   uint2* __restrict__ qtab,
                                                   uint2* __restrict__ l7tab,
                                                   const float2* __restrict__ coords,
                                                   u32* __restrict__ gcount, int S) {
    if (blockIdx.x < PREP_TBLOCKS) {
        const int total = QTOT + L7TEX;
        for (int t = blockIdx.x * 256 + threadIdx.x; t < total; t += PREP_TBLOCKS * 256) {
            if (t < QTOT) {
                int L = 0;
#pragma unroll
                for (int i = 1; i < 7; ++i) if (t >= c_cum[i]) L = i;
                int i   = t - c_cum[L];
                int res = c_res[L];
                int rr  = res * res;
                int y   = i / res, x = i - y * res;
                int xn  = min(x + 1, res - 1), yn = min(y + 1, res - 1);
                const float* cb = p.cb[L];
                int i00 = y * res + x,  i01 = y * res + xn;
                int i10 = yn * res + x, i11 = yn * res + xn;
                uint2 q0, q1, q2, q3;
                q0.x = pack_h2(cb[i00], cb[i00 + rr]);
                q0.y = pack_h2(cb[i00 + 2 * rr], cb[i00 + 3 * rr]);
                q1.x = pack_h2(cb[i01], cb[i01 + rr]);
                q1.y = pack_h2(cb[i01 + 2 * rr], cb[i01 + 3 * rr]);
                q2.x = pack_h2(cb[i10], cb[i10 + rr]);
                q2.y = pack_h2(cb[i10 + 2 * rr], cb[i10 + 3 * rr]);
                q3.x = pack_h2(cb[i11], cb[i11 + rr]);
                q3.y = pack_h2(cb[i11 + 2 * rr], cb[i11 + 3 * rr]);
                uint2* q = qtab + 4 * (size_t)t;
                q[0] = q0; q[1] = q1; q[2] = q2; q[3] = q3;
            } else {
                int i  = t - QTOT;
                const float* cb = p.cb[7];
                uint2 tex;
                tex.x = pack_h2(cb[i], cb[i + L7TEX]);
                tex.y = pack_h2(cb[i + 2 * L7TEX], cb[i + 3 * L7TEX]);
                l7tab[i] = tex;
            }
        }
    } else {
        __shared__ u32 h[NBANDS];
        for (int i = threadIdx.x; i < NBANDS; i += 256) h[i] = 0u;
        __syncthreads();
        int nb = gridDim.x - PREP_TBLOCKS;
        for (int s = (blockIdx.x - PREP_TBLOCKS) * 256 + threadIdx.x; s < S; s += nb * 256)
            atomicAdd(&h[band_of(coords[s].y)], 1u);
        __syncthreads();
        for (int i = threadIdx.x; i < NBANDS; i += 256)
            if (h[i]) atomicAdd(&gcount[i], h[i]);
    }
}

__global__ __launch_bounds__(64) void zero_counts(u32* gcount) {
    gcount[threadIdx.x] = 0u;
}

__global__ __launch_bounds__(64) void scan_kernel(const u32* __restrict__ gcount,
                                                  u32* __restrict__ gcursor) {
    if (threadIdx.x == 0) {
        u32 acc = 0;
        for (int i = 0; i < NBANDS; ++i) { gcursor[i] = acc; acc += gcount[i]; }
    }
}

__global__ __launch_bounds__(256) void scatter_kernel(const float2* __restrict__ coords,
                                                      u32* __restrict__ gcursor,
                                                      float2* __restrict__ coordsS,
                                                      int*    __restrict__ idxS, int S) {
    __shared__ u32 h[NBANDS];
    __shared__ u32 rank_base[NBANDS];
    int s0 = blockIdx.x * CHUNK;
    for (int i = threadIdx.x; i < NBANDS; i += 256) h[i] = 0u;
    __syncthreads();
    u32 myrank[CHUNK / 256];
    int myk[CHUNK / 256];
    float2 myc[CHUNK / 256];
#pragma unroll
    for (int it = 0; it < CHUNK / 256; ++it) {
        int s = s0 + it * 256 + threadIdx.x;
        if (s < S) {
            float2 c = coords[s];
            int k = band_of(c.y);
            myc[it] = c;
            myk[it] = k;
            myrank[it] = atomicAdd(&h[k], 1u);
        }
    }
    __syncthreads();
    for (int i = threadIdx.x; i < NBANDS; i += 256)
        rank_base[i] = h[i] ? atomicAdd(&gcursor[i], h[i]) : 0u;
    __syncthreads();
#pragma unroll
    for (int it = 0; it < CHUNK / 256; ++it) {
        int s = s0 + it * 256 + threadIdx.x;
        if (s < S) {
            u32 pos = rank_base[myk[it]] + myrank[it];
            coordsS[pos] = myc[it];
            idxS[pos]    = s;
        }
    }
}

// ------- main: band-sorted, 8 threads per sample (one per level), quad gathers -------
// Levels 0-6: one 32-B quad load (two 16-B halves of the SAME 64-B line -> 1 line
// touch). Level 7: row-pair (2 lines). 9 line-touches/sample vs 16 before.
// Store: 8 lanes x 16 B = full contiguous 128 B per sample within one instruction.
__global__ __launch_bounds__(256) void grid_sorted8(const f32x2* __restrict__ coordsS,
                                                    const int*   __restrict__ idxS,
                                                    const uint2* __restrict__ qtab,
                                                    const uint2* __restrict__ l7tab,
                                                    f32x4* __restrict__ out, int S) {
    // XCD-contiguous swizzle (gridDim.x multiple of 8)
    int p  = blockIdx.x;
    int nb = gridDim.x;
    int b  = (p & 7) * (nb >> 3) + (p >> 3);
    int t  = b * 256 + threadIdx.x;
    int s  = t >> 3;
    if (s >= S) return;
    int L  = t & 7;

    f32x2 c = coordsS[s];
    int idx = idxS[s];

    int   res   = c_res[L];
    float scale = c_scale[L];
    float px = (c.x + 1.0f) * scale;
    float py = (c.y + 1.0f) * scale;
    float xf = floorf(px), yf = floorf(py);
    float wx = px - xf,    wy = py - yf;
    int x0 = (int)xf, y0 = (int)yf;
    int xp = min(max(x0, 0), res - 2);  wx += (float)(x0 - xp);
    int yp = min(max(y0, 0), res - 2);  wy += (float)(y0 - yp);

    u32x4a8 h0, h1;
    if (L < 7) {
        const u32x4a8* q = (const u32x4a8*)(qtab + 4 * (size_t)(c_cum[L] + yp * res + xp));
        h0 = q[0];            // t00, t01
        h1 = q[1];            // t10, t11
    } else {
        const uint2* r0 = l7tab + yp * L7RES + xp;
        h0 = *(const u32x4a8*)r0;
        h1 = *(const u32x4a8*)(r0 + L7RES);
    }

    float2 a00 = up_h2(h0.x), b00 = up_h2(h0.y);
    float2 a01 = up_h2(h0.z), b01 = up_h2(h0.w);
    float2 a10 = up_h2(h1.x), b10 = up_h2(h1.y);
    float2 a11 = up_h2(h1.z), b11 = up_h2(h1.w);

    float w00 = (1.0f - wx) * (1.0f - wy);
    float w01 = wx * (1.0f - wy);
    float w10 = (1.0f - wx) * wy;
    float w11 = wx * wy;

    f32x4 r;
    r.x = a00.x * w00 + a01.x * w01 + a10.x * w10 + a11.x * w11;
    r.y = a00.y * w00 + a01.y * w01 + a10.y * w10 + a11.y * w11;
    r.z = b00.x * w00 + b01.x * w01 + b10.x * w10 + b11.x * w11;
    r.w = b00.y * w00 + b01.y * w01 + b10.y * w10 + b11.y * w11;

    out[(size_t)idx * 8 + L] = r;
}

// ---------------- generic fallback (levels != 8 or ws too small, raw fp32 cbs) ----------------
__global__ __launch_bounds__(256) void grid_generic(const float2* __restrict__ coords,
                                                    CbPtrs p, float4* __restrict__ out4,
                                                    int S, int levels) {
    int s = blockIdx.x * 256 + threadIdx.x;
    if (s >= S) return;
    float2 c = coords[s];
    for (int L = 0; L < levels; ++L) {
        int   res   = c_res[L];
        float scale = c_scale[L];
        float px = (c.x + 1.0f) * scale;
        float py = (c.y + 1.0f) * scale;
        float x0f = floorf(px), y0f = floorf(py);
        float wx = px - x0f,    wy = py - y0f;
        int rm1 = res - 1;
        int x0 = min(max((int)x0f, 0), rm1);
        int x1 = min(x0 + 1, rm1);
        int y0 = min(max((int)y0f, 0), rm1);
        int y1 = min(y0 + 1, rm1);
        int i00 = y0 * res + x0, i01 = y0 * res + x1, i10 = y1 * res + x0, i11 = y1 * res + x1;
        float w00 = (1.0f - wx) * (1.0f - wy);
        float w01 = wx * (1.0f - wy);
        float w10 = (1.0f - wx) * wy;
        float w11 = wx * wy;
        float4 r;
        const float* cb = p.cb[L];
        int rr = res * res;
        float* pr = &r.x;
#pragma unroll
        for (int f = 0; f < 4; ++f) {
            const float* cf = cb + f * rr;
            pr[f] = cf[i00] * w00 + cf[i01] * w01 + cf[i10] * w10 + cf[i11] * w11;
        }
        out4[(size_t)s * levels + L] = r;
    }
}

extern "C" void kernel_launch(void* const* d_in, const int* in_sizes, int n_in,
                              void* d_out, int out_size, void* d_ws, size_t ws_size,
                              hipStream_t stream) {
    const float2* coords = (const float2*)d_in[0];
    int S = in_sizes[0] / 2;                 // total samples B*N
    int levels = out_size / (S * 4);

    CbPtrs ptrs;
    for (int i = 0; i < NLEVELS; ++i) ptrs.cb[i] = (const float*)d_in[2 + i];

    // ws layout: qtab | l7tab | gcount[64] gcursor[64] | coordsS | idxS
    size_t tab_bytes  = (QTAB_BYTES + L7TAB_BYTES + 255) & ~(size_t)255;
    size_t cnt_bytes  = 1024;
    size_t crd_bytes  = (size_t)S * 8;
    size_t idx_bytes  = (size_t)S * 4;
    size_t need = tab_bytes + cnt_bytes + crd_bytes + idx_bytes;

    char* ws = (char*)d_ws;
    uint2*  qtab    = (uint2*)ws;
    uint2*  l7tab   = (uint2*)(ws + QTAB_BYTES);
    u32*    gcount  = (u32*)(ws + tab_bytes);
    u32*    gcursor = gcount + NBANDS;
    float2* coordsS = (float2*)(ws + tab_bytes + cnt_bytes);
    int*    idxS    = (int*)(ws + tab_bytes + cnt_bytes + crd_bytes);

    if (levels != NLEVELS || ws_size < need) {
        int blocks = (S + 255) / 256;
        grid_generic<<<blocks, 256, 0, stream>>>(coords, ptrs, (float4*)d_out, S, levels);
        return;
    }

    zero_counts<<<1, 64, 0, stream>>>(gcount);
    prep_kernel<<<PREP_TBLOCKS + 512, 256, 0, stream>>>(ptrs, qtab, l7tab, coords, gcount, S);
    scan_kernel<<<1, 64, 0, stream>>>(gcount, gcursor);
    int nchunk = (S + CHUNK - 1) / CHUNK;
    scatter_kernel<<<nchunk, 256, 0, stream>>>(coords, gcursor, coordsS, idxS, S);
    long long total = (long long)S * 8;
    int nb = (int)((total + 255) / 256);
    nb = ((nb + 7) / 8) * 8;                 // multiple of 8 for bijective swizzle
    grid_sorted8<<<nb, 256, 0, stream>>>((const f32x2*)coordsS, idxS, qtab, l7tab,
                                         (f32x4*)d_out, S);
}